// Round 3
// baseline (7505.370 us; speedup 1.0000x reference)
//
#include <hip/hip_runtime.h>
#include <math.h>

#define B_SZ   4096
#define T_SZ   60
#define F_SZ   30
#define H_ENC  256
#define HD_DEC 100
#define LATD   256
#define DIN_P  76    // 74 padded to multiple of 4
#define DEC_IN 279   // 256 + 9 + 14
#define DEC_IN_P 280

// ---------------- workspace layout (float offsets) ----------------
enum {
  OFF_WIHT_F = 0,                          // [76][1024]
  OFF_WHHT_F = OFF_WIHT_F + 76*1024,       // [256][1024]
  OFF_WIHT_B = OFF_WHHT_F + 256*1024,
  OFF_WHHT_B = OFF_WIHT_B + 76*1024,
  OFF_WLATT  = OFF_WHHT_B + 256*1024,      // [256][512]
  OFF_WIHT1  = OFF_WLATT  + 256*512,       // [280][400]
  OFF_WHHT1  = OFF_WIHT1  + 280*400,       // [100][400]
  OFF_WIHT2  = OFF_WHHT1  + 100*400,       // [100][400]
  OFF_WHHT2  = OFF_WIHT2  + 100*400,       // [100][400]
  OFF_WG1T   = OFF_WHHT2  + 100*400,       // [100][25]
  OFF_BE_F   = OFF_WG1T   + 100*25,        // [1024]
  OFF_BE_B   = OFF_BE_F   + 1024,
  OFF_BE1    = OFF_BE_B   + 1024,          // [400]
  OFF_BE2    = OFF_BE1    + 400,
  OFF_HF     = OFF_BE2    + 400,           // [4096][256]
  OFF_HB     = OFF_HF     + B_SZ*H_ENC,
  OFF_Z      = OFF_HB     + B_SZ*H_ENC,    // [4096][256]
  OFF_H1     = OFF_Z      + B_SZ*LATD,     // [4096][100]
  OFF_C1     = OFF_H1     + B_SZ*HD_DEC,
  OFF_H2     = OFF_C1     + B_SZ*HD_DEC,
  OFF_C2     = OFF_H2     + B_SZ*HD_DEC,
  OFF_DLQ    = OFF_C2     + B_SZ*HD_DEC,   // [4096][9]
  OFF_XBUF   = OFF_DLQ    + B_SZ*9,        // [4096][25]
  OFF_MU     = OFF_XBUF   + B_SZ*25,       // [25]
  OFF_RSTD   = OFF_MU     + 25,
  WS_FLOATS  = OFF_RSTD   + 25
};

__device__ __forceinline__ float sigf(float x) { return 1.0f / (1.0f + expf(-x)); }

// ---------------- prep: transposes + bias sums ----------------
struct TJob { const float* src; const float* src2; float* dst; int R, C, Cp; };
struct PrepArgs { TJob j[14]; };

__global__ __launch_bounds__(256) void prep_kernel(PrepArgs a) {
  int g = blockIdx.x * blockDim.x + threadIdx.x;
  int stride = gridDim.x * blockDim.x;
  for (int jj = 0; jj < 14; ++jj) {
    TJob jb = a.j[jj];
    if (jb.src2) {                      // bias sum job
      for (int i = g; i < jb.R; i += stride) jb.dst[i] = jb.src[i] + jb.src2[i];
    } else {                            // transpose job: dst[cp][r] = src[r][cp], zero-pad rows cp>=C
      int total = jb.Cp * jb.R;
      for (int i = g; i < total; i += stride) {
        int cp = i / jb.R, r = i - cp * jb.R;
        jb.dst[i] = (cp < jb.C) ? jb.src[r * jb.C + cp] : 0.0f;
      }
    }
  }
}

// ---------------- encoder: both directions, persistent over T ----------------
// 512 blocks: [0,256) forward over batch slices of 16, [256,512) backward.
// Thread u owns hidden unit u (all 4 gates); 16 batch rows per block.
// seq_len is globally sorted descending -> per-block early exit at maxlen.
__global__ __launch_bounds__(256) void enc_kernel(
    const float* __restrict__ seq, const int* __restrict__ seq_len,
    const int* __restrict__ ymd, const int* __restrict__ acq,
    const float* __restrict__ Ea0, const float* __restrict__ Ea1, const float* __restrict__ Ea2,
    const float* __restrict__ Es0, const float* __restrict__ Es1, const float* __restrict__ Es2,
    const float* __restrict__ WihT_f, const float* __restrict__ WhhT_f, const float* __restrict__ be_f,
    const float* __restrict__ WihT_b, const float* __restrict__ WhhT_b, const float* __restrict__ be_b,
    float* __restrict__ hf_out, float* __restrict__ hb_out)
{
  const int tid = threadIdx.x;
  const bool bwd = blockIdx.x >= 256;
  const int b0 = (blockIdx.x & 255) * 16;
  const float* __restrict__ WihT = bwd ? WihT_b : WihT_f;
  const float* __restrict__ WhhT = bwd ? WhhT_b : WhhT_f;
  const float* __restrict__ be   = bwd ? be_b   : be_f;
  float* __restrict__ hout = bwd ? hb_out : hf_out;

  __shared__ float x_s[16][80];        // DIN padded; cols 74..79 stay 0
  __shared__ float h_s[16][H_ENC];
  __shared__ int   len_s[16];
  __shared__ int   maxlen_s;

  for (int i = tid; i < 16 * 80; i += 256) (&x_s[0][0])[i] = 0.0f;
  for (int i = tid; i < 16 * H_ENC; i += 256) (&h_s[0][0])[i] = 0.0f;
  if (tid < 16) len_s[tid] = seq_len[b0 + tid];
  __syncthreads();

  if (tid == 0) {
    int m = 0;
    for (int r = 0; r < 16; ++r) m = max(m, len_s[r]);
    maxlen_s = m;
  }

  // acquisition embeddings (constant over t): x[30..57]
  for (int i = tid; i < 16 * 28; i += 256) {
    int r = i / 28, j = i - r * 28;
    const int* aq = &acq[(b0 + r) * 3];
    float v;
    if (j < 16)      v = Ea0[aq[0] * 16 + j];
    else if (j < 24) v = Ea1[aq[1] * 8 + (j - 16)];
    else             v = Ea2[aq[2] * 4 + (j - 24)];
    x_s[r][30 + j] = v;
  }

  const int u = tid;
  const float bi0 = be[u], bi1 = be[256 + u], bi2 = be[512 + u], bi3 = be[768 + u];
  float c_r[16];
  #pragma unroll
  for (int r = 0; r < 16; ++r) c_r[r] = 0.0f;

  __syncthreads();
  const int maxlen = maxlen_s;

  for (int t = 0; t < maxlen; ++t) {
    // ---- stage x (seq features + date embeddings) ----
    for (int i = tid; i < 16 * F_SZ; i += 256) {
      int r = i / F_SZ, k = i - r * F_SZ;
      int len = len_s[r];
      int te = bwd ? max(len - 1 - t, 0) : t;
      x_s[r][k] = seq[((b0 + r) * T_SZ + te) * F_SZ + k];
    }
    {
      int r = tid >> 4, j = tid & 15;   // 256 == 16 rows * 16 vals
      int len = len_s[r];
      int te = bwd ? max(len - 1 - t, 0) : t;
      const int* ym = &ymd[((b0 + r) * T_SZ + te) * 3];
      float v;
      if (j < 8)       v = Es0[ym[0] * 8 + j];
      else if (j < 12) v = Es1[ym[1] * 4 + (j - 8)];
      else             v = Es2[ym[2] * 4 + (j - 12)];
      x_s[r][58 + j] = v;
    }
    __syncthreads();

    // ---- gates: thread u computes all 4 gates of unit u for 16 rows ----
    float a0[16], a1[16], a2[16], a3[16];
    #pragma unroll
    for (int r = 0; r < 16; ++r) { a0[r] = bi0; a1[r] = bi1; a2[r] = bi2; a3[r] = bi3; }

    for (int k = 0; k < DIN_P; k += 4) {
      float w0[4], w1[4], w2[4], w3[4];
      #pragma unroll
      for (int dk = 0; dk < 4; ++dk) {
        const float* wr = WihT + (k + dk) * 1024 + u;
        w0[dk] = wr[0]; w1[dk] = wr[256]; w2[dk] = wr[512]; w3[dk] = wr[768];
      }
      #pragma unroll
      for (int r = 0; r < 16; ++r) {
        const float4 xv = *reinterpret_cast<const float4*>(&x_s[r][k]);
        a0[r] += w0[0]*xv.x + w0[1]*xv.y + w0[2]*xv.z + w0[3]*xv.w;
        a1[r] += w1[0]*xv.x + w1[1]*xv.y + w1[2]*xv.z + w1[3]*xv.w;
        a2[r] += w2[0]*xv.x + w2[1]*xv.y + w2[2]*xv.z + w2[3]*xv.w;
        a3[r] += w3[0]*xv.x + w3[1]*xv.y + w3[2]*xv.z + w3[3]*xv.w;
      }
    }
    for (int k = 0; k < H_ENC; k += 4) {
      float w0[4], w1[4], w2[4], w3[4];
      #pragma unroll
      for (int dk = 0; dk < 4; ++dk) {
        const float* wr = WhhT + (k + dk) * 1024 + u;
        w0[dk] = wr[0]; w1[dk] = wr[256]; w2[dk] = wr[512]; w3[dk] = wr[768];
      }
      #pragma unroll
      for (int r = 0; r < 16; ++r) {
        const float4 hv = *reinterpret_cast<const float4*>(&h_s[r][k]);
        a0[r] += w0[0]*hv.x + w0[1]*hv.y + w0[2]*hv.z + w0[3]*hv.w;
        a1[r] += w1[0]*hv.x + w1[1]*hv.y + w1[2]*hv.z + w1[3]*hv.w;
        a2[r] += w2[0]*hv.x + w2[1]*hv.y + w2[2]*hv.z + w2[3]*hv.w;
        a3[r] += w3[0]*hv.x + w3[1]*hv.y + w3[2]*hv.z + w3[3]*hv.w;
      }
    }

    // ---- cell update (masked) ----
    #pragma unroll
    for (int r = 0; r < 16; ++r) {
      if (t < len_s[r]) {
        float ig = sigf(a0[r]);
        float fg = sigf(a1[r]);
        float gg = tanhf(a2[r]);
        float og = sigf(a3[r]);
        float cn = fg * c_r[r] + ig * gg;
        c_r[r] = cn;
        a0[r] = og * tanhf(cn);
      }
    }
    __syncthreads();                     // all h_s reads of this step done
    #pragma unroll
    for (int r = 0; r < 16; ++r) if (t < len_s[r]) h_s[r][u] = a0[r];
    __syncthreads();                     // new h visible; x_s safe to overwrite
  }

  #pragma unroll
  for (int r = 0; r < 16; ++r) hout[(b0 + r) * H_ENC + u] = h_s[r][u];
}

// ---------------- latent: lat = (hf+hb)@WlatT + b; z; dlq0; zero decoder state ----------------
__global__ __launch_bounds__(256) void latent_kernel(
    const float* __restrict__ hf, const float* __restrict__ hb,
    const float* __restrict__ WlatT, const float* __restrict__ b_lat,
    const float* __restrict__ z_noise, const float* __restrict__ seq,
    const int* __restrict__ seq_len,
    float* __restrict__ z, float* __restrict__ dlq,
    float* __restrict__ h1w, float* __restrict__ c1w,
    float* __restrict__ h2w, float* __restrict__ c2w)
{
  const int tid = threadIdx.x;
  const int b0 = blockIdx.x * 16;
  __shared__ float hs[16][H_ENC];
  for (int i = tid; i < 16 * H_ENC; i += 256)
    (&hs[0][0])[i] = hf[b0 * H_ENC + i] + hb[b0 * H_ENC + i];
  __syncthreads();

  const int u = tid;
  const float bm = b_lat[u], bv = b_lat[LATD + u];
  float am[16], av[16];
  #pragma unroll
  for (int r = 0; r < 16; ++r) { am[r] = bm; av[r] = bv; }

  for (int k = 0; k < H_ENC; k += 4) {
    float wm[4], wv[4];
    #pragma unroll
    for (int dk = 0; dk < 4; ++dk) {
      const float* wr = WlatT + (k + dk) * 512;
      wm[dk] = wr[u]; wv[dk] = wr[256 + u];
    }
    #pragma unroll
    for (int r = 0; r < 16; ++r) {
      const float4 hv = *reinterpret_cast<const float4*>(&hs[r][k]);
      am[r] += wm[0]*hv.x + wm[1]*hv.y + wm[2]*hv.z + wm[3]*hv.w;
      av[r] += wv[0]*hv.x + wv[1]*hv.y + wv[2]*hv.z + wv[3]*hv.w;
    }
  }
  #pragma unroll
  for (int r = 0; r < 16; ++r) {
    int b = b0 + r;
    z[b * LATD + u] = am[r] + sqrtf(expf(av[r])) * z_noise[b * LATD + u];
  }
  if (u < HD_DEC) {
    #pragma unroll
    for (int r = 0; r < 16; ++r) {
      int b = b0 + r;
      h1w[b * HD_DEC + u] = 0.0f; c1w[b * HD_DEC + u] = 0.0f;
      h2w[b * HD_DEC + u] = 0.0f; c2w[b * HD_DEC + u] = 0.0f;
    }
  }
  if (u < 9) {
    #pragma unroll
    for (int r = 0; r < 16; ++r) {
      int b = b0 + r;
      int len = seq_len[b];
      dlq[b * 9 + u] = seq[(b * T_SZ + (len - 1)) * F_SZ + 21 + u];
    }
  }
}

// ---------------- decoder cell step: LSTM1 + LSTM2 + x=relu(h2@Wg1T+bg1) ----------------
__global__ __launch_bounds__(256) void dec_cell_kernel(
    const float* __restrict__ z, const float* __restrict__ dlq,
    const float* __restrict__ macro,
    float* __restrict__ h1w, float* __restrict__ c1w,
    float* __restrict__ h2w, float* __restrict__ c2w,
    const float* __restrict__ WihT1, const float* __restrict__ WhhT1, const float* __restrict__ be1,
    const float* __restrict__ WihT2, const float* __restrict__ WhhT2, const float* __restrict__ be2,
    const float* __restrict__ Wg1T, const float* __restrict__ bg1,
    float* __restrict__ xbuf, int t)
{
  const int tid = threadIdx.x;
  const int b0 = blockIdx.x * 16;
  __shared__ float di[16][DEC_IN_P];
  __shared__ float h1s[16][HD_DEC];
  __shared__ float h2s[16][HD_DEC];

  for (int i = tid; i < 16 * DEC_IN_P; i += 256) {
    int r = i / DEC_IN_P, k = i - r * DEC_IN_P;
    int b = b0 + r;
    float v;
    if (k < LATD)            v = z[b * LATD + k];
    else if (k < LATD + 9)   v = dlq[b * 9 + (k - LATD)];
    else if (k < DEC_IN)     v = macro[(b * 12 + t) * 14 + (k - LATD - 9)];
    else                     v = 0.0f;
    di[r][k] = v;
  }
  for (int i = tid; i < 16 * HD_DEC; i += 256) {
    int r = i / HD_DEC, k = i - r * HD_DEC;
    h1s[r][k] = h1w[(b0 + r) * HD_DEC + k];
    h2s[r][k] = h2w[(b0 + r) * HD_DEC + k];
  }

  const int u = tid & 127;
  const int grp = tid >> 7;       // 0/1 -> rows [0..8) / [8..16)
  const int r0 = grp * 8;
  const bool act = u < HD_DEC;

  float c1r[8], c2r[8];
  if (act) {
    #pragma unroll
    for (int r = 0; r < 8; ++r) {
      c1r[r] = c1w[(b0 + r0 + r) * HD_DEC + u];
      c2r[r] = c2w[(b0 + r0 + r) * HD_DEC + u];
    }
  }
  __syncthreads();

  // ---- LSTM1 gates ----
  float a0[8], a1[8], a2[8], a3[8];
  if (act) {
    const float b0g = be1[u], b1g = be1[100 + u], b2g = be1[200 + u], b3g = be1[300 + u];
    #pragma unroll
    for (int r = 0; r < 8; ++r) { a0[r] = b0g; a1[r] = b1g; a2[r] = b2g; a3[r] = b3g; }
    for (int k = 0; k < DEC_IN_P; k += 4) {
      float w0[4], w1[4], w2[4], w3[4];
      #pragma unroll
      for (int dk = 0; dk < 4; ++dk) {
        const float* wr = WihT1 + (k + dk) * 400 + u;
        w0[dk] = wr[0]; w1[dk] = wr[100]; w2[dk] = wr[200]; w3[dk] = wr[300];
      }
      #pragma unroll
      for (int r = 0; r < 8; ++r) {
        const float4 xv = *reinterpret_cast<const float4*>(&di[r0 + r][k]);
        a0[r] += w0[0]*xv.x + w0[1]*xv.y + w0[2]*xv.z + w0[3]*xv.w;
        a1[r] += w1[0]*xv.x + w1[1]*xv.y + w1[2]*xv.z + w1[3]*xv.w;
        a2[r] += w2[0]*xv.x + w2[1]*xv.y + w2[2]*xv.z + w2[3]*xv.w;
        a3[r] += w3[0]*xv.x + w3[1]*xv.y + w3[2]*xv.z + w3[3]*xv.w;
      }
    }
    for (int k = 0; k < HD_DEC; k += 4) {
      float w0[4], w1[4], w2[4], w3[4];
      #pragma unroll
      for (int dk = 0; dk < 4; ++dk) {
        const float* wr = WhhT1 + (k + dk) * 400 + u;
        w0[dk] = wr[0]; w1[dk] = wr[100]; w2[dk] = wr[200]; w3[dk] = wr[300];
      }
      #pragma unroll
      for (int r = 0; r < 8; ++r) {
        const float4 hv = *reinterpret_cast<const float4*>(&h1s[r0 + r][k]);
        a0[r] += w0[0]*hv.x + w0[1]*hv.y + w0[2]*hv.z + w0[3]*hv.w;
        a1[r] += w1[0]*hv.x + w1[1]*hv.y + w1[2]*hv.z + w1[3]*hv.w;
        a2[r] += w2[0]*hv.x + w2[1]*hv.y + w2[2]*hv.z + w2[3]*hv.w;
        a3[r] += w3[0]*hv.x + w3[1]*hv.y + w3[2]*hv.z + w3[3]*hv.w;
      }
    }
  }
  __syncthreads();                 // h1s reads complete
  if (act) {
    #pragma unroll
    for (int r = 0; r < 8; ++r) {
      float ig = sigf(a0[r]), fg = sigf(a1[r]), gg = tanhf(a2[r]), og = sigf(a3[r]);
      float cn = fg * c1r[r] + ig * gg;
      float hn = og * tanhf(cn);
      int b = b0 + r0 + r;
      h1s[r0 + r][u] = hn;
      h1w[b * HD_DEC + u] = hn;
      c1w[b * HD_DEC + u] = cn;
    }
  }
  __syncthreads();                 // new h1 visible

  // ---- LSTM2 gates (x = new h1, h = old h2) ----
  if (act) {
    const float b0g = be2[u], b1g = be2[100 + u], b2g = be2[200 + u], b3g = be2[300 + u];
    #pragma unroll
    for (int r = 0; r < 8; ++r) { a0[r] = b0g; a1[r] = b1g; a2[r] = b2g; a3[r] = b3g; }
    for (int k = 0; k < HD_DEC; k += 4) {
      float w0[4], w1[4], w2[4], w3[4];
      #pragma unroll
      for (int dk = 0; dk < 4; ++dk) {
        const float* wr = WihT2 + (k + dk) * 400 + u;
        w0[dk] = wr[0]; w1[dk] = wr[100]; w2[dk] = wr[200]; w3[dk] = wr[300];
      }
      #pragma unroll
      for (int r = 0; r < 8; ++r) {
        const float4 hv = *reinterpret_cast<const float4*>(&h1s[r0 + r][k]);
        a0[r] += w0[0]*hv.x + w0[1]*hv.y + w0[2]*hv.z + w0[3]*hv.w;
        a1[r] += w1[0]*hv.x + w1[1]*hv.y + w1[2]*hv.z + w1[3]*hv.w;
        a2[r] += w2[0]*hv.x + w2[1]*hv.y + w2[2]*hv.z + w2[3]*hv.w;
        a3[r] += w3[0]*hv.x + w3[1]*hv.y + w3[2]*hv.z + w3[3]*hv.w;
      }
    }
    for (int k = 0; k < HD_DEC; k += 4) {
      float w0[4], w1[4], w2[4], w3[4];
      #pragma unroll
      for (int dk = 0; dk < 4; ++dk) {
        const float* wr = WhhT2 + (k + dk) * 400 + u;
        w0[dk] = wr[0]; w1[dk] = wr[100]; w2[dk] = wr[200]; w3[dk] = wr[300];
      }
      #pragma unroll
      for (int r = 0; r < 8; ++r) {
        const float4 hv = *reinterpret_cast<const float4*>(&h2s[r0 + r][k]);
        a0[r] += w0[0]*hv.x + w0[1]*hv.y + w0[2]*hv.z + w0[3]*hv.w;
        a1[r] += w1[0]*hv.x + w1[1]*hv.y + w1[2]*hv.z + w1[3]*hv.w;
        a2[r] += w2[0]*hv.x + w2[1]*hv.y + w2[2]*hv.z + w2[3]*hv.w;
        a3[r] += w3[0]*hv.x + w3[1]*hv.y + w3[2]*hv.z + w3[3]*hv.w;
      }
    }
  }
  __syncthreads();                 // h2s reads complete
  if (act) {
    #pragma unroll
    for (int r = 0; r < 8; ++r) {
      float ig = sigf(a0[r]), fg = sigf(a1[r]), gg = tanhf(a2[r]), og = sigf(a3[r]);
      float cn = fg * c2r[r] + ig * gg;
      float hn = og * tanhf(cn);
      int b = b0 + r0 + r;
      h2s[r0 + r][u] = hn;
      h2w[b * HD_DEC + u] = hn;
      c2w[b * HD_DEC + u] = cn;
    }
  }
  __syncthreads();                 // new h2 visible

  // ---- x = relu(h2 @ Wg1T + bg1) ----
  for (int p = tid; p < 16 * 25; p += 256) {
    int r = p / 25, c = p - r * 25;
    float s = bg1[c];
    for (int k = 0; k < HD_DEC; k += 4) {
      const float4 hv = *reinterpret_cast<const float4*>(&h2s[r][k]);
      s += hv.x * Wg1T[k * 25 + c] + hv.y * Wg1T[(k + 1) * 25 + c]
         + hv.z * Wg1T[(k + 2) * 25 + c] + hv.w * Wg1T[(k + 3) * 25 + c];
    }
    xbuf[(b0 + r) * 25 + c] = fmaxf(s, 0.0f);
  }
}

// ---------------- decoder batchnorm stats (deterministic tree reduce) ----------------
__global__ __launch_bounds__(256) void dec_stats_kernel(
    const float* __restrict__ xbuf, float* __restrict__ muv, float* __restrict__ rstdv)
{
  const int col = blockIdx.x;
  const int tid = threadIdx.x;
  __shared__ float red[256];
  float v[16];
  float s = 0.0f;
  #pragma unroll
  for (int i = 0; i < 16; ++i) { v[i] = xbuf[(tid + 256 * i) * 25 + col]; s += v[i]; }
  red[tid] = s; __syncthreads();
  for (int off = 128; off >= 1; off >>= 1) {
    if (tid < off) red[tid] += red[tid + off];
    __syncthreads();
  }
  float mean = red[0] / (float)B_SZ;
  __syncthreads();
  float s2 = 0.0f;
  #pragma unroll
  for (int i = 0; i < 16; ++i) { float d = v[i] - mean; s2 += d * d; }
  red[tid] = s2; __syncthreads();
  for (int off = 128; off >= 1; off >>= 1) {
    if (tid < off) red[tid] += red[tid + off];
    __syncthreads();
  }
  if (tid == 0) {
    muv[col] = mean;
    rstdv[col] = rsqrtf(red[0] / (float)B_SZ + 1e-5f);
  }
}

// ---------------- decoder normalize + dlq = xn@Wg2T + bg2, write output ----------------
__global__ __launch_bounds__(256) void dec_out_kernel(
    const float* __restrict__ xbuf, const float* __restrict__ muv, const float* __restrict__ rstdv,
    const float* __restrict__ gamma, const float* __restrict__ beta,
    const float* __restrict__ Wg2, const float* __restrict__ bg2,
    float* __restrict__ dlq, float* __restrict__ out, int t)
{
  int b = blockIdx.x * 256 + threadIdx.x;
  float xn[25];
  #pragma unroll
  for (int c = 0; c < 25; ++c)
    xn[c] = gamma[c] * (xbuf[b * 25 + c] - muv[c]) * rstdv[c] + beta[c];
  #pragma unroll
  for (int j = 0; j < 9; ++j) {
    float s = bg2[j];
    #pragma unroll
    for (int c = 0; c < 25; ++c) s += xn[c] * Wg2[j * 25 + c];
    dlq[b * 9 + j] = s;
    out[b * 108 + j * 12 + t] = s;
  }
}

// ---------------- host launch ----------------
extern "C" void kernel_launch(void* const* d_in, const int* in_sizes, int n_in,
                              void* d_out, int out_size, void* d_ws, size_t ws_size,
                              hipStream_t stream)
{
  const float* seq     = (const float*)d_in[0];
  const int*   seq_len = (const int*)  d_in[1];
  const int*   ymd     = (const int*)  d_in[2];
  const int*   acq     = (const int*)  d_in[3];
  const float* macro   = (const float*)d_in[4];
  const float* z_noise = (const float*)d_in[5];
  const float* Ea0 = (const float*)d_in[6];
  const float* Ea1 = (const float*)d_in[7];
  const float* Ea2 = (const float*)d_in[8];
  const float* Es0 = (const float*)d_in[9];
  const float* Es1 = (const float*)d_in[10];
  const float* Es2 = (const float*)d_in[11];
  const float* Wih_f = (const float*)d_in[12];
  const float* Whh_f = (const float*)d_in[13];
  const float* bih_f = (const float*)d_in[14];
  const float* bhh_f = (const float*)d_in[15];
  const float* Wih_b = (const float*)d_in[16];
  const float* Whh_b = (const float*)d_in[17];
  const float* bih_b = (const float*)d_in[18];
  const float* bhh_b = (const float*)d_in[19];
  const float* W_lat = (const float*)d_in[20];
  const float* b_lat = (const float*)d_in[21];
  const float* Wih1  = (const float*)d_in[22];
  const float* Whh1  = (const float*)d_in[23];
  const float* bih1  = (const float*)d_in[24];
  const float* bhh1  = (const float*)d_in[25];
  const float* Wih2  = (const float*)d_in[26];
  const float* Whh2  = (const float*)d_in[27];
  const float* bih2  = (const float*)d_in[28];
  const float* bhh2  = (const float*)d_in[29];
  const float* Wg1   = (const float*)d_in[30];
  const float* bg1   = (const float*)d_in[31];
  const float* gamma = (const float*)d_in[32];
  const float* beta  = (const float*)d_in[33];
  const float* Wg2   = (const float*)d_in[34];
  const float* bg2   = (const float*)d_in[35];

  float* ws  = (float*)d_ws;
  float* out = (float*)d_out;

  float* wihT_f = ws + OFF_WIHT_F;
  float* whhT_f = ws + OFF_WHHT_F;
  float* wihT_b = ws + OFF_WIHT_B;
  float* whhT_b = ws + OFF_WHHT_B;
  float* wlatT  = ws + OFF_WLATT;
  float* wihT1  = ws + OFF_WIHT1;
  float* whhT1  = ws + OFF_WHHT1;
  float* wihT2  = ws + OFF_WIHT2;
  float* whhT2  = ws + OFF_WHHT2;
  float* wg1T   = ws + OFF_WG1T;
  float* be_f   = ws + OFF_BE_F;
  float* be_b   = ws + OFF_BE_B;
  float* be1    = ws + OFF_BE1;
  float* be2    = ws + OFF_BE2;
  float* hf     = ws + OFF_HF;
  float* hb     = ws + OFF_HB;
  float* z      = ws + OFF_Z;
  float* h1w    = ws + OFF_H1;
  float* c1w    = ws + OFF_C1;
  float* h2w    = ws + OFF_H2;
  float* c2w    = ws + OFF_C2;
  float* dlq    = ws + OFF_DLQ;
  float* xbuf   = ws + OFF_XBUF;
  float* muv    = ws + OFF_MU;
  float* rstdv  = ws + OFF_RSTD;

  PrepArgs pa;
  int ji = 0;
  auto TP = [&](const float* s, float* d, int R, int C, int Cp) {
    pa.j[ji].src = s; pa.j[ji].src2 = nullptr; pa.j[ji].dst = d;
    pa.j[ji].R = R; pa.j[ji].C = C; pa.j[ji].Cp = Cp; ++ji;
  };
  auto BS = [&](const float* a, const float* b, float* d, int n) {
    pa.j[ji].src = a; pa.j[ji].src2 = b; pa.j[ji].dst = d;
    pa.j[ji].R = n; pa.j[ji].C = 0; pa.j[ji].Cp = 0; ++ji;
  };
  TP(Wih_f, wihT_f, 1024, 74, 76);
  TP(Whh_f, whhT_f, 1024, 256, 256);
  TP(Wih_b, wihT_b, 1024, 74, 76);
  TP(Whh_b, whhT_b, 1024, 256, 256);
  TP(W_lat, wlatT, 512, 256, 256);
  TP(Wih1,  wihT1, 400, 279, 280);
  TP(Whh1,  whhT1, 400, 100, 100);
  TP(Wih2,  wihT2, 400, 100, 100);
  TP(Whh2,  whhT2, 400, 100, 100);
  TP(Wg1,   wg1T,  25, 100, 100);
  BS(bih_f, bhh_f, be_f, 1024);
  BS(bih_b, bhh_b, be_b, 1024);
  BS(bih1,  bhh1,  be1,  400);
  BS(bih2,  bhh2,  be2,  400);

  prep_kernel<<<512, 256, 0, stream>>>(pa);

  enc_kernel<<<512, 256, 0, stream>>>(
      seq, seq_len, ymd, acq, Ea0, Ea1, Ea2, Es0, Es1, Es2,
      wihT_f, whhT_f, be_f, wihT_b, whhT_b, be_b, hf, hb);

  latent_kernel<<<256, 256, 0, stream>>>(
      hf, hb, wlatT, b_lat, z_noise, seq, seq_len,
      z, dlq, h1w, c1w, h2w, c2w);

  for (int t = 0; t < 12; ++t) {
    dec_cell_kernel<<<256, 256, 0, stream>>>(
        z, dlq, macro, h1w, c1w, h2w, c2w,
        wihT1, whhT1, be1, wihT2, whhT2, be2, wg1T, bg1, xbuf, t);
    dec_stats_kernel<<<25, 256, 0, stream>>>(xbuf, muv, rstdv);
    dec_out_kernel<<<16, 256, 0, stream>>>(
        xbuf, muv, rstdv, gamma, beta, Wg2, bg2, dlq, out, t);
  }
}

// Round 4
// 6500.218 us; speedup vs baseline: 1.1546x; 1.1546x over previous
//
#include <hip/hip_runtime.h>
#include <math.h>

#define B_SZ   4096
#define T_SZ   60
#define F_SZ   30
#define H_ENC  256
#define HD_DEC 100
#define LATD   256
#define DIN_P  76    // 74 padded to multiple of 4
#define DEC_IN 279   // 256 + 9 + 14
#define DEC_IN_P 280

// ---------------- workspace layout (float offsets) ----------------
// Packed weights: [k][unit][gate] float4 (gate-interleaved) for coalesced 16B loads.
enum {
  OFF_PIH_F = 0,                            // 76*256 float4
  OFF_PHH_F = OFF_PIH_F + 76*256*4,         // 256*256 float4
  OFF_PIH_B = OFF_PHH_F + 256*256*4,
  OFF_PHH_B = OFF_PIH_B + 76*256*4,
  OFF_PLAT  = OFF_PHH_B + 256*256*4,        // 256*256 float2 {mu,lv}
  OFF_P1I   = OFF_PLAT  + 256*256*2,        // 280*100 float4
  OFF_P1H   = OFF_P1I   + 280*100*4,        // 100*100 float4
  OFF_P2I   = OFF_P1H   + 100*100*4,
  OFF_P2H   = OFF_P2I   + 100*100*4,
  OFF_WG1T  = OFF_P2H   + 100*100*4,        // [100][25]
  OFF_BE_F  = OFF_WG1T  + 100*25,           // [1024]
  OFF_BE_B  = OFF_BE_F  + 1024,
  OFF_BE1   = OFF_BE_B  + 1024,             // [400]
  OFF_BE2   = OFF_BE1   + 400,
  OFF_HF    = OFF_BE2   + 400,              // [4096][256]
  OFF_HB    = OFF_HF    + B_SZ*H_ENC,
  OFF_Z     = OFF_HB    + B_SZ*H_ENC,       // [4096][256]
  OFF_H1    = OFF_Z     + B_SZ*LATD,        // [4096][100]
  OFF_C1    = OFF_H1    + B_SZ*HD_DEC,
  OFF_H2    = OFF_C1    + B_SZ*HD_DEC,
  OFF_C2    = OFF_H2    + B_SZ*HD_DEC,
  OFF_DLQ   = OFF_C2    + B_SZ*HD_DEC,      // [4096][9]
  OFF_XBUF  = OFF_DLQ   + B_SZ*9,           // [4096][25]
  OFF_MU    = OFF_XBUF  + B_SZ*25,          // [25]
  OFF_RSTD  = OFF_MU    + 25,
  WS_FLOATS = OFF_RSTD  + 25
};

__device__ __forceinline__ float sigf(float x) { return 1.0f / (1.0f + expf(-x)); }

// ---------------- prep: gate-interleaved packs + bias sums ----------------
// pack job: dst[(k*U+u)*G+g] = (k<C) ? src[(g*U+u)*C + k] : 0   for k<Kp
// bias job (src2!=null): dst[i] = src[i]+src2[i], i<U
struct PJob { const float* src; const float* src2; float* dst; int U, C, Kp, G; };
struct PrepArgs { PJob j[14]; };

__global__ __launch_bounds__(256) void prep_kernel(PrepArgs a) {
  int gtid = blockIdx.x * blockDim.x + threadIdx.x;
  int stride = gridDim.x * blockDim.x;
  for (int jj = 0; jj < 14; ++jj) {
    PJob jb = a.j[jj];
    if (jb.src2) {
      for (int i = gtid; i < jb.U; i += stride) jb.dst[i] = jb.src[i] + jb.src2[i];
    } else {
      int total = jb.Kp * jb.U;
      for (int i = gtid; i < total; i += stride) {
        int k = i / jb.U, u = i - k * jb.U;
        float* d = jb.dst + (size_t)i * jb.G;
        for (int g = 0; g < jb.G; ++g)
          d[g] = (k < jb.C) ? jb.src[(g * jb.U + u) * jb.C + k] : 0.0f;
      }
    }
  }
}

// ---------------- encoder: both directions, persistent over T ----------------
// 1024 blocks: [0,512) forward over batch slices of 8, [512,1024) backward.
// Thread u owns hidden unit u (all 4 gates); 8 batch rows per block.
// Packed weights: float4 {i,f,g,o} at [k*256+u].
__global__ __launch_bounds__(256, 4) void enc_kernel(
    const float* __restrict__ seq, const int* __restrict__ seq_len,
    const int* __restrict__ ymd, const int* __restrict__ acq,
    const float* __restrict__ Ea0, const float* __restrict__ Ea1, const float* __restrict__ Ea2,
    const float* __restrict__ Es0, const float* __restrict__ Es1, const float* __restrict__ Es2,
    const float4* __restrict__ PihF, const float4* __restrict__ PhhF, const float* __restrict__ be_f,
    const float4* __restrict__ PihB, const float4* __restrict__ PhhB, const float* __restrict__ be_b,
    float* __restrict__ hf_out, float* __restrict__ hb_out)
{
  const int tid = threadIdx.x;
  const bool bwd = blockIdx.x >= 512;
  const int b0 = (blockIdx.x & 511) * 8;
  const float4* __restrict__ Pih = bwd ? PihB : PihF;
  const float4* __restrict__ Phh = bwd ? PhhB : PhhF;
  const float* __restrict__ be   = bwd ? be_b : be_f;
  float* __restrict__ hout = bwd ? hb_out : hf_out;

  __shared__ float x_s[8][80];         // DIN padded; cols 74..79 stay 0
  __shared__ float h_s[8][H_ENC];
  __shared__ int   len_s[8];
  __shared__ int   maxlen_s;

  for (int i = tid; i < 8 * 80; i += 256) (&x_s[0][0])[i] = 0.0f;
  for (int i = tid; i < 8 * H_ENC; i += 256) (&h_s[0][0])[i] = 0.0f;
  if (tid < 8) len_s[tid] = seq_len[b0 + tid];
  __syncthreads();

  if (tid == 0) {
    int m = 0;
    for (int r = 0; r < 8; ++r) m = max(m, len_s[r]);
    maxlen_s = m;
  }

  // acquisition embeddings (constant over t): x[30..57]
  if (tid < 8 * 28) {
    int r = tid / 28, j = tid - r * 28;
    const int* aq = &acq[(b0 + r) * 3];
    float v;
    if (j < 16)      v = Ea0[aq[0] * 16 + j];
    else if (j < 24) v = Ea1[aq[1] * 8 + (j - 16)];
    else             v = Ea2[aq[2] * 4 + (j - 24)];
    x_s[r][30 + j] = v;
  }

  const int u = tid;
  const float bi0 = be[u], bi1 = be[256 + u], bi2 = be[512 + u], bi3 = be[768 + u];
  float c_r[8];
  #pragma unroll
  for (int r = 0; r < 8; ++r) c_r[r] = 0.0f;

  __syncthreads();
  const int maxlen = maxlen_s;

  for (int t = 0; t < maxlen; ++t) {
    // ---- stage x (seq features + date embeddings) ----
    if (tid < 8 * F_SZ) {
      int r = tid / F_SZ, k = tid - r * F_SZ;
      int len = len_s[r];
      int te = bwd ? max(len - 1 - t, 0) : t;
      x_s[r][k] = seq[((b0 + r) * T_SZ + te) * F_SZ + k];
    }
    if (tid < 8 * 16) {
      int r = tid >> 4, j = tid & 15;
      int len = len_s[r];
      int te = bwd ? max(len - 1 - t, 0) : t;
      const int* ym = &ymd[((b0 + r) * T_SZ + te) * 3];
      float v;
      if (j < 8)       v = Es0[ym[0] * 8 + j];
      else if (j < 12) v = Es1[ym[1] * 4 + (j - 8)];
      else             v = Es2[ym[2] * 4 + (j - 12)];
      x_s[r][58 + j] = v;
    }
    __syncthreads();

    // ---- gates: thread u computes all 4 gates of unit u for 8 rows ----
    float a0[8], a1[8], a2[8], a3[8];
    #pragma unroll
    for (int r = 0; r < 8; ++r) { a0[r] = bi0; a1[r] = bi1; a2[r] = bi2; a3[r] = bi3; }

    for (int k = 0; k < DIN_P; k += 4) {
      const float4 w0 = Pih[(k + 0) * 256 + u];
      const float4 w1 = Pih[(k + 1) * 256 + u];
      const float4 w2 = Pih[(k + 2) * 256 + u];
      const float4 w3 = Pih[(k + 3) * 256 + u];
      #pragma unroll
      for (int r = 0; r < 8; ++r) {
        const float4 xv = *reinterpret_cast<const float4*>(&x_s[r][k]);
        a0[r] += w0.x*xv.x + w1.x*xv.y + w2.x*xv.z + w3.x*xv.w;
        a1[r] += w0.y*xv.x + w1.y*xv.y + w2.y*xv.z + w3.y*xv.w;
        a2[r] += w0.z*xv.x + w1.z*xv.y + w2.z*xv.z + w3.z*xv.w;
        a3[r] += w0.w*xv.x + w1.w*xv.y + w2.w*xv.z + w3.w*xv.w;
      }
    }
    for (int k = 0; k < H_ENC; k += 4) {
      const float4 w0 = Phh[(k + 0) * 256 + u];
      const float4 w1 = Phh[(k + 1) * 256 + u];
      const float4 w2 = Phh[(k + 2) * 256 + u];
      const float4 w3 = Phh[(k + 3) * 256 + u];
      #pragma unroll
      for (int r = 0; r < 8; ++r) {
        const float4 hv = *reinterpret_cast<const float4*>(&h_s[r][k]);
        a0[r] += w0.x*hv.x + w1.x*hv.y + w2.x*hv.z + w3.x*hv.w;
        a1[r] += w0.y*hv.x + w1.y*hv.y + w2.y*hv.z + w3.y*hv.w;
        a2[r] += w0.z*hv.x + w1.z*hv.y + w2.z*hv.z + w3.z*hv.w;
        a3[r] += w0.w*hv.x + w1.w*hv.y + w2.w*hv.z + w3.w*hv.w;
      }
    }

    // ---- cell update (masked) ----
    #pragma unroll
    for (int r = 0; r < 8; ++r) {
      if (t < len_s[r]) {
        float ig = sigf(a0[r]);
        float fg = sigf(a1[r]);
        float gg = tanhf(a2[r]);
        float og = sigf(a3[r]);
        float cn = fg * c_r[r] + ig * gg;
        c_r[r] = cn;
        a0[r] = og * tanhf(cn);
      }
    }
    __syncthreads();                     // all h_s reads of this step done
    #pragma unroll
    for (int r = 0; r < 8; ++r) if (t < len_s[r]) h_s[r][u] = a0[r];
    __syncthreads();                     // new h visible; x_s safe to overwrite
  }

  #pragma unroll
  for (int r = 0; r < 8; ++r) hout[(b0 + r) * H_ENC + u] = h_s[r][u];
}

// ---------------- latent: lat = (hf+hb)@WlatT + b; z; dlq0; zero decoder state ----------------
__global__ __launch_bounds__(256) void latent_kernel(
    const float* __restrict__ hf, const float* __restrict__ hb,
    const float2* __restrict__ Plat, const float* __restrict__ b_lat,
    const float* __restrict__ z_noise, const float* __restrict__ seq,
    const int* __restrict__ seq_len,
    float* __restrict__ z, float* __restrict__ dlq,
    float* __restrict__ h1w, float* __restrict__ c1w,
    float* __restrict__ h2w, float* __restrict__ c2w)
{
  const int tid = threadIdx.x;
  const int b0 = blockIdx.x * 16;
  __shared__ float hs[16][H_ENC];
  for (int i = tid; i < 16 * H_ENC; i += 256)
    (&hs[0][0])[i] = hf[b0 * H_ENC + i] + hb[b0 * H_ENC + i];
  __syncthreads();

  const int u = tid;
  const float bm = b_lat[u], bv = b_lat[LATD + u];
  float am[16], av[16];
  #pragma unroll
  for (int r = 0; r < 16; ++r) { am[r] = bm; av[r] = bv; }

  for (int k = 0; k < H_ENC; k += 4) {
    const float2 p0 = Plat[(k + 0) * 256 + u];
    const float2 p1 = Plat[(k + 1) * 256 + u];
    const float2 p2 = Plat[(k + 2) * 256 + u];
    const float2 p3 = Plat[(k + 3) * 256 + u];
    #pragma unroll
    for (int r = 0; r < 16; ++r) {
      const float4 hv = *reinterpret_cast<const float4*>(&hs[r][k]);
      am[r] += p0.x*hv.x + p1.x*hv.y + p2.x*hv.z + p3.x*hv.w;
      av[r] += p0.y*hv.x + p1.y*hv.y + p2.y*hv.z + p3.y*hv.w;
    }
  }
  #pragma unroll
  for (int r = 0; r < 16; ++r) {
    int b = b0 + r;
    z[b * LATD + u] = am[r] + sqrtf(expf(av[r])) * z_noise[b * LATD + u];
  }
  if (u < HD_DEC) {
    #pragma unroll
    for (int r = 0; r < 16; ++r) {
      int b = b0 + r;
      h1w[b * HD_DEC + u] = 0.0f; c1w[b * HD_DEC + u] = 0.0f;
      h2w[b * HD_DEC + u] = 0.0f; c2w[b * HD_DEC + u] = 0.0f;
    }
  }
  if (u < 9) {
    #pragma unroll
    for (int r = 0; r < 16; ++r) {
      int b = b0 + r;
      int len = seq_len[b];
      dlq[b * 9 + u] = seq[(b * T_SZ + (len - 1)) * F_SZ + 21 + u];
    }
  }
}

// ---------------- decoder cell step: LSTM1 + LSTM2 + x=relu(h2@Wg1T+bg1) ----------------
__global__ __launch_bounds__(256) void dec_cell_kernel(
    const float* __restrict__ z, const float* __restrict__ dlq,
    const float* __restrict__ macro,
    float* __restrict__ h1w, float* __restrict__ c1w,
    float* __restrict__ h2w, float* __restrict__ c2w,
    const float4* __restrict__ P1I, const float4* __restrict__ P1H, const float* __restrict__ be1,
    const float4* __restrict__ P2I, const float4* __restrict__ P2H, const float* __restrict__ be2,
    const float* __restrict__ Wg1T, const float* __restrict__ bg1,
    float* __restrict__ xbuf, int t)
{
  const int tid = threadIdx.x;
  const int b0 = blockIdx.x * 16;
  __shared__ float di[16][DEC_IN_P];
  __shared__ float h1s[16][HD_DEC];
  __shared__ float h2s[16][HD_DEC];

  for (int i = tid; i < 16 * DEC_IN_P; i += 256) {
    int r = i / DEC_IN_P, k = i - r * DEC_IN_P;
    int b = b0 + r;
    float v;
    if (k < LATD)            v = z[b * LATD + k];
    else if (k < LATD + 9)   v = dlq[b * 9 + (k - LATD)];
    else if (k < DEC_IN)     v = macro[(b * 12 + t) * 14 + (k - LATD - 9)];
    else                     v = 0.0f;
    di[r][k] = v;
  }
  for (int i = tid; i < 16 * HD_DEC; i += 256) {
    int r = i / HD_DEC, k = i - r * HD_DEC;
    h1s[r][k] = h1w[(b0 + r) * HD_DEC + k];
    h2s[r][k] = h2w[(b0 + r) * HD_DEC + k];
  }

  const int u = tid & 127;
  const int grp = tid >> 7;       // 0/1 -> rows [0..8) / [8..16)
  const int r0 = grp * 8;
  const bool act = u < HD_DEC;

  float c1r[8], c2r[8];
  if (act) {
    #pragma unroll
    for (int r = 0; r < 8; ++r) {
      c1r[r] = c1w[(b0 + r0 + r) * HD_DEC + u];
      c2r[r] = c2w[(b0 + r0 + r) * HD_DEC + u];
    }
  }
  __syncthreads();

  // ---- LSTM1 gates ----
  float a0[8], a1[8], a2[8], a3[8];
  if (act) {
    const float b0g = be1[u], b1g = be1[100 + u], b2g = be1[200 + u], b3g = be1[300 + u];
    #pragma unroll
    for (int r = 0; r < 8; ++r) { a0[r] = b0g; a1[r] = b1g; a2[r] = b2g; a3[r] = b3g; }
    for (int k = 0; k < DEC_IN_P; k += 4) {
      const float4 w0 = P1I[(k + 0) * 100 + u];
      const float4 w1 = P1I[(k + 1) * 100 + u];
      const float4 w2 = P1I[(k + 2) * 100 + u];
      const float4 w3 = P1I[(k + 3) * 100 + u];
      #pragma unroll
      for (int r = 0; r < 8; ++r) {
        const float4 xv = *reinterpret_cast<const float4*>(&di[r0 + r][k]);
        a0[r] += w0.x*xv.x + w1.x*xv.y + w2.x*xv.z + w3.x*xv.w;
        a1[r] += w0.y*xv.x + w1.y*xv.y + w2.y*xv.z + w3.y*xv.w;
        a2[r] += w0.z*xv.x + w1.z*xv.y + w2.z*xv.z + w3.z*xv.w;
        a3[r] += w0.w*xv.x + w1.w*xv.y + w2.w*xv.z + w3.w*xv.w;
      }
    }
    for (int k = 0; k < HD_DEC; k += 4) {
      const float4 w0 = P1H[(k + 0) * 100 + u];
      const float4 w1 = P1H[(k + 1) * 100 + u];
      const float4 w2 = P1H[(k + 2) * 100 + u];
      const float4 w3 = P1H[(k + 3) * 100 + u];
      #pragma unroll
      for (int r = 0; r < 8; ++r) {
        const float4 hv = *reinterpret_cast<const float4*>(&h1s[r0 + r][k]);
        a0[r] += w0.x*hv.x + w1.x*hv.y + w2.x*hv.z + w3.x*hv.w;
        a1[r] += w0.y*hv.x + w1.y*hv.y + w2.y*hv.z + w3.y*hv.w;
        a2[r] += w0.z*hv.x + w1.z*hv.y + w2.z*hv.z + w3.z*hv.w;
        a3[r] += w0.w*hv.x + w1.w*hv.y + w2.w*hv.z + w3.w*hv.w;
      }
    }
  }
  __syncthreads();                 // h1s reads complete
  if (act) {
    #pragma unroll
    for (int r = 0; r < 8; ++r) {
      float ig = sigf(a0[r]), fg = sigf(a1[r]), gg = tanhf(a2[r]), og = sigf(a3[r]);
      float cn = fg * c1r[r] + ig * gg;
      float hn = og * tanhf(cn);
      int b = b0 + r0 + r;
      h1s[r0 + r][u] = hn;
      h1w[b * HD_DEC + u] = hn;
      c1w[b * HD_DEC + u] = cn;
    }
  }
  __syncthreads();                 // new h1 visible

  // ---- LSTM2 gates (x = new h1, h = old h2) ----
  if (act) {
    const float b0g = be2[u], b1g = be2[100 + u], b2g = be2[200 + u], b3g = be2[300 + u];
    #pragma unroll
    for (int r = 0; r < 8; ++r) { a0[r] = b0g; a1[r] = b1g; a2[r] = b2g; a3[r] = b3g; }
    for (int k = 0; k < HD_DEC; k += 4) {
      const float4 w0 = P2I[(k + 0) * 100 + u];
      const float4 w1 = P2I[(k + 1) * 100 + u];
      const float4 w2 = P2I[(k + 2) * 100 + u];
      const float4 w3 = P2I[(k + 3) * 100 + u];
      #pragma unroll
      for (int r = 0; r < 8; ++r) {
        const float4 hv = *reinterpret_cast<const float4*>(&h1s[r0 + r][k]);
        a0[r] += w0.x*hv.x + w1.x*hv.y + w2.x*hv.z + w3.x*hv.w;
        a1[r] += w0.y*hv.x + w1.y*hv.y + w2.y*hv.z + w3.y*hv.w;
        a2[r] += w0.z*hv.x + w1.z*hv.y + w2.z*hv.z + w3.z*hv.w;
        a3[r] += w0.w*hv.x + w1.w*hv.y + w2.w*hv.z + w3.w*hv.w;
      }
    }
    for (int k = 0; k < HD_DEC; k += 4) {
      const float4 w0 = P2H[(k + 0) * 100 + u];
      const float4 w1 = P2H[(k + 1) * 100 + u];
      const float4 w2 = P2H[(k + 2) * 100 + u];
      const float4 w3 = P2H[(k + 3) * 100 + u];
      #pragma unroll
      for (int r = 0; r < 8; ++r) {
        const float4 hv = *reinterpret_cast<const float4*>(&h2s[r0 + r][k]);
        a0[r] += w0.x*hv.x + w1.x*hv.y + w2.x*hv.z + w3.x*hv.w;
        a1[r] += w0.y*hv.x + w1.y*hv.y + w2.y*hv.z + w3.y*hv.w;
        a2[r] += w0.z*hv.x + w1.z*hv.y + w2.z*hv.z + w3.z*hv.w;
        a3[r] += w0.w*hv.x + w1.w*hv.y + w2.w*hv.z + w3.w*hv.w;
      }
    }
  }
  __syncthreads();                 // h2s reads complete
  if (act) {
    #pragma unroll
    for (int r = 0; r < 8; ++r) {
      float ig = sigf(a0[r]), fg = sigf(a1[r]), gg = tanhf(a2[r]), og = sigf(a3[r]);
      float cn = fg * c2r[r] + ig * gg;
      float hn = og * tanhf(cn);
      int b = b0 + r0 + r;
      h2s[r0 + r][u] = hn;
      h2w[b * HD_DEC + u] = hn;
      c2w[b * HD_DEC + u] = cn;
    }
  }
  __syncthreads();                 // new h2 visible

  // ---- x = relu(h2 @ Wg1T + bg1) ----
  for (int p = tid; p < 16 * 25; p += 256) {
    int r = p / 25, c = p - r * 25;
    float s = bg1[c];
    for (int k = 0; k < HD_DEC; k += 4) {
      const float4 hv = *reinterpret_cast<const float4*>(&h2s[r][k]);
      s += hv.x * Wg1T[k * 25 + c] + hv.y * Wg1T[(k + 1) * 25 + c]
         + hv.z * Wg1T[(k + 2) * 25 + c] + hv.w * Wg1T[(k + 3) * 25 + c];
    }
    xbuf[(b0 + r) * 25 + c] = fmaxf(s, 0.0f);
  }
}

// ---------------- decoder batchnorm stats (deterministic tree reduce) ----------------
__global__ __launch_bounds__(256) void dec_stats_kernel(
    const float* __restrict__ xbuf, float* __restrict__ muv, float* __restrict__ rstdv)
{
  const int col = blockIdx.x;
  const int tid = threadIdx.x;
  __shared__ float red[256];
  float v[16];
  float s = 0.0f;
  #pragma unroll
  for (int i = 0; i < 16; ++i) { v[i] = xbuf[(tid + 256 * i) * 25 + col]; s += v[i]; }
  red[tid] = s; __syncthreads();
  for (int off = 128; off >= 1; off >>= 1) {
    if (tid < off) red[tid] += red[tid + off];
    __syncthreads();
  }
  float mean = red[0] / (float)B_SZ;
  __syncthreads();
  float s2 = 0.0f;
  #pragma unroll
  for (int i = 0; i < 16; ++i) { float d = v[i] - mean; s2 += d * d; }
  red[tid] = s2; __syncthreads();
  for (int off = 128; off >= 1; off >>= 1) {
    if (tid < off) red[tid] += red[tid + off];
    __syncthreads();
  }
  if (tid == 0) {
    muv[col] = mean;
    rstdv[col] = rsqrtf(red[0] / (float)B_SZ + 1e-5f);
  }
}

// ---------------- decoder normalize + dlq = xn@Wg2T + bg2, write output ----------------
__global__ __launch_bounds__(256) void dec_out_kernel(
    const float* __restrict__ xbuf, const float* __restrict__ muv, const float* __restrict__ rstdv,
    const float* __restrict__ gamma, const float* __restrict__ beta,
    const float* __restrict__ Wg2, const float* __restrict__ bg2,
    float* __restrict__ dlq, float* __restrict__ out, int t)
{
  int b = blockIdx.x * 256 + threadIdx.x;
  float xn[25];
  #pragma unroll
  for (int c = 0; c < 25; ++c)
    xn[c] = gamma[c] * (xbuf[b * 25 + c] - muv[c]) * rstdv[c] + beta[c];
  #pragma unroll
  for (int j = 0; j < 9; ++j) {
    float s = bg2[j];
    #pragma unroll
    for (int c = 0; c < 25; ++c) s += xn[c] * Wg2[j * 25 + c];
    dlq[b * 9 + j] = s;
    out[b * 108 + j * 12 + t] = s;
  }
}

// ---------------- host launch ----------------
extern "C" void kernel_launch(void* const* d_in, const int* in_sizes, int n_in,
                              void* d_out, int out_size, void* d_ws, size_t ws_size,
                              hipStream_t stream)
{
  const float* seq     = (const float*)d_in[0];
  const int*   seq_len = (const int*)  d_in[1];
  const int*   ymd     = (const int*)  d_in[2];
  const int*   acq     = (const int*)  d_in[3];
  const float* macro   = (const float*)d_in[4];
  const float* z_noise = (const float*)d_in[5];
  const float* Ea0 = (const float*)d_in[6];
  const float* Ea1 = (const float*)d_in[7];
  const float* Ea2 = (const float*)d_in[8];
  const float* Es0 = (const float*)d_in[9];
  const float* Es1 = (const float*)d_in[10];
  const float* Es2 = (const float*)d_in[11];
  const float* Wih_f = (const float*)d_in[12];
  const float* Whh_f = (const float*)d_in[13];
  const float* bih_f = (const float*)d_in[14];
  const float* bhh_f = (const float*)d_in[15];
  const float* Wih_b = (const float*)d_in[16];
  const float* Whh_b = (const float*)d_in[17];
  const float* bih_b = (const float*)d_in[18];
  const float* bhh_b = (const float*)d_in[19];
  const float* W_lat = (const float*)d_in[20];
  const float* b_lat = (const float*)d_in[21];
  const float* Wih1  = (const float*)d_in[22];
  const float* Whh1  = (const float*)d_in[23];
  const float* bih1  = (const float*)d_in[24];
  const float* bhh1  = (const float*)d_in[25];
  const float* Wih2  = (const float*)d_in[26];
  const float* Whh2  = (const float*)d_in[27];
  const float* bih2  = (const float*)d_in[28];
  const float* bhh2  = (const float*)d_in[29];
  const float* Wg1   = (const float*)d_in[30];
  const float* bg1   = (const float*)d_in[31];
  const float* gamma = (const float*)d_in[32];
  const float* beta  = (const float*)d_in[33];
  const float* Wg2   = (const float*)d_in[34];
  const float* bg2   = (const float*)d_in[35];

  float* ws  = (float*)d_ws;
  float* out = (float*)d_out;

  float* pihF = ws + OFF_PIH_F;
  float* phhF = ws + OFF_PHH_F;
  float* pihB = ws + OFF_PIH_B;
  float* phhB = ws + OFF_PHH_B;
  float* plat = ws + OFF_PLAT;
  float* p1i  = ws + OFF_P1I;
  float* p1h  = ws + OFF_P1H;
  float* p2i  = ws + OFF_P2I;
  float* p2h  = ws + OFF_P2H;
  float* wg1T = ws + OFF_WG1T;
  float* be_f = ws + OFF_BE_F;
  float* be_b = ws + OFF_BE_B;
  float* be1  = ws + OFF_BE1;
  float* be2  = ws + OFF_BE2;
  float* hf   = ws + OFF_HF;
  float* hb   = ws + OFF_HB;
  float* z    = ws + OFF_Z;
  float* h1w  = ws + OFF_H1;
  float* c1w  = ws + OFF_C1;
  float* h2w  = ws + OFF_H2;
  float* c2w  = ws + OFF_C2;
  float* dlq  = ws + OFF_DLQ;
  float* xbuf = ws + OFF_XBUF;
  float* muv  = ws + OFF_MU;
  float* rstdv= ws + OFF_RSTD;

  PrepArgs pa;
  int ji = 0;
  auto PK = [&](const float* s, float* d, int U, int C, int Kp, int G) {
    pa.j[ji].src = s; pa.j[ji].src2 = nullptr; pa.j[ji].dst = d;
    pa.j[ji].U = U; pa.j[ji].C = C; pa.j[ji].Kp = Kp; pa.j[ji].G = G; ++ji;
  };
  auto BS = [&](const float* a, const float* b, float* d, int n) {
    pa.j[ji].src = a; pa.j[ji].src2 = b; pa.j[ji].dst = d;
    pa.j[ji].U = n; pa.j[ji].C = 0; pa.j[ji].Kp = 0; pa.j[ji].G = 0; ++ji;
  };
  PK(Wih_f, pihF, 256, 74, 76, 4);
  PK(Whh_f, phhF, 256, 256, 256, 4);
  PK(Wih_b, pihB, 256, 74, 76, 4);
  PK(Whh_b, phhB, 256, 256, 256, 4);
  PK(W_lat, plat, 256, 256, 256, 2);
  PK(Wih1,  p1i,  100, 279, 280, 4);
  PK(Whh1,  p1h,  100, 100, 100, 4);
  PK(Wih2,  p2i,  100, 100, 100, 4);
  PK(Whh2,  p2h,  100, 100, 100, 4);
  PK(Wg1,   wg1T, 25, 100, 100, 1);
  BS(bih_f, bhh_f, be_f, 1024);
  BS(bih_b, bhh_b, be_b, 1024);
  BS(bih1,  bhh1,  be1,  400);
  BS(bih2,  bhh2,  be2,  400);

  prep_kernel<<<512, 256, 0, stream>>>(pa);

  enc_kernel<<<1024, 256, 0, stream>>>(
      seq, seq_len, ymd, acq, Ea0, Ea1, Ea2, Es0, Es1, Es2,
      (const float4*)pihF, (const float4*)phhF, be_f,
      (const float4*)pihB, (const float4*)phhB, be_b, hf, hb);

  latent_kernel<<<256, 256, 0, stream>>>(
      hf, hb, (const float2*)plat, b_lat, z_noise, seq, seq_len,
      z, dlq, h1w, c1w, h2w, c2w);

  for (int t = 0; t < 12; ++t) {
    dec_cell_kernel<<<256, 256, 0, stream>>>(
        z, dlq, macro, h1w, c1w, h2w, c2w,
        (const float4*)p1i, (const float4*)p1h, be1,
        (const float4*)p2i, (const float4*)p2h, be2, wg1T, bg1, xbuf, t);
    dec_stats_kernel<<<25, 256, 0, stream>>>(xbuf, muv, rstdv);
    dec_out_kernel<<<16, 256, 0, stream>>>(
        xbuf, muv, rstdv, gamma, beta, Wg2, bg2, dlq, out, t);
  }
}

// Round 5
// 5486.031 us; speedup vs baseline: 1.3681x; 1.1849x over previous
//
#include <hip/hip_runtime.h>
#include <math.h>

#define B_SZ   4096
#define T_SZ   60
#define F_SZ   30
#define H_ENC  256
#define HD_DEC 100
#define LATD   256
#define DIN_P  76    // 74 padded to multiple of 4
#define DEC_IN 279   // 256 + 9 + 14
#define DEC_IN_P 280

// ---------------- workspace layout (float offsets) ----------------
// Packed weights: [k][unit][gate] float4 (gate-interleaved) for coalesced 16B loads.
enum {
  OFF_PIH_F = 0,                            // 76*256 float4
  OFF_PHH_F = OFF_PIH_F + 76*256*4,         // 256*256 float4
  OFF_PIH_B = OFF_PHH_F + 256*256*4,
  OFF_PHH_B = OFF_PIH_B + 76*256*4,
  OFF_PLAT  = OFF_PHH_B + 256*256*4,        // 256*256 float2 {mu,lv}
  OFF_P1I   = OFF_PLAT  + 256*256*2,        // 280*100 float4
  OFF_P1H   = OFF_P1I   + 280*100*4,        // 100*100 float4
  OFF_P2I   = OFF_P1H   + 100*100*4,
  OFF_P2H   = OFF_P2I   + 100*100*4,
  OFF_WG1T  = OFF_P2H   + 100*100*4,        // [100][25]
  OFF_BE_F  = OFF_WG1T  + 100*25,           // [1024]
  OFF_BE_B  = OFF_BE_F  + 1024,
  OFF_BE1   = OFF_BE_B  + 1024,             // [400]
  OFF_BE2   = OFF_BE1   + 400,
  OFF_HF    = OFF_BE2   + 400,              // [4096][256]
  OFF_HB    = OFF_HF    + B_SZ*H_ENC,
  OFF_Z     = OFF_HB    + B_SZ*H_ENC,       // [4096][256]
  OFF_H1    = OFF_Z     + B_SZ*LATD,        // [4096][100]
  OFF_C1    = OFF_H1    + B_SZ*HD_DEC,
  OFF_H2    = OFF_C1    + B_SZ*HD_DEC,
  OFF_C2    = OFF_H2    + B_SZ*HD_DEC,
  OFF_DLQ   = OFF_C2    + B_SZ*HD_DEC,      // [4096][9]
  OFF_XBUF  = OFF_DLQ   + B_SZ*9,           // [4096][25]
  OFF_MU    = OFF_XBUF  + B_SZ*25,          // [25]
  OFF_RSTD  = OFF_MU    + 25,
  WS_FLOATS = OFF_RSTD  + 25
};

__device__ __forceinline__ float sigf(float x) { return 1.0f / (1.0f + expf(-x)); }

// ---------------- prep: gate-interleaved packs + bias sums ----------------
// pack job: dst[(k*U+u)*G+g] = (k<C) ? src[(g*U+u)*C + k] : 0   for k<Kp
// bias job (src2!=null): dst[i] = src[i]+src2[i], i<U
struct PJob { const float* src; const float* src2; float* dst; int U, C, Kp, G; };
struct PrepArgs { PJob j[14]; };

__global__ __launch_bounds__(256) void prep_kernel(PrepArgs a) {
  int gtid = blockIdx.x * blockDim.x + threadIdx.x;
  int stride = gridDim.x * blockDim.x;
  for (int jj = 0; jj < 14; ++jj) {
    PJob jb = a.j[jj];
    if (jb.src2) {
      for (int i = gtid; i < jb.U; i += stride) jb.dst[i] = jb.src[i] + jb.src2[i];
    } else {
      int total = jb.Kp * jb.U;
      for (int i = gtid; i < total; i += stride) {
        int k = i / jb.U, u = i - k * jb.U;
        float* d = jb.dst + (size_t)i * jb.G;
        for (int g = 0; g < jb.G; ++g)
          d[g] = (k < jb.C) ? jb.src[(g * jb.U + u) * jb.C + k] : 0.0f;
      }
    }
  }
}

// ---------------- encoder: both directions, persistent over T ----------------
// 1024 blocks: [0,512) forward over batch slices of 8, [512,1024) backward.
// Thread u owns hidden unit u (all 4 gates); 8 batch rows per block.
// Packed weights: float4 {i,f,g,o} at [k*256+u].
// NOTE: no min-waves clamp in __launch_bounds__ — round-4's (256,4) forced
// VGPR=64 and spilled ~1.1 GB/dispatch to scratch (FETCH 624MB/WRITE 515MB).
__global__ __launch_bounds__(256) void enc_kernel(
    const float* __restrict__ seq, const int* __restrict__ seq_len,
    const int* __restrict__ ymd, const int* __restrict__ acq,
    const float* __restrict__ Ea0, const float* __restrict__ Ea1, const float* __restrict__ Ea2,
    const float* __restrict__ Es0, const float* __restrict__ Es1, const float* __restrict__ Es2,
    const float4* __restrict__ PihF, const float4* __restrict__ PhhF, const float* __restrict__ be_f,
    const float4* __restrict__ PihB, const float4* __restrict__ PhhB, const float* __restrict__ be_b,
    float* __restrict__ hf_out, float* __restrict__ hb_out)
{
  const int tid = threadIdx.x;
  const bool bwd = blockIdx.x >= 512;
  const int b0 = (blockIdx.x & 511) * 8;
  const float4* __restrict__ Pih = bwd ? PihB : PihF;
  const float4* __restrict__ Phh = bwd ? PhhB : PhhF;
  const float* __restrict__ be   = bwd ? be_b : be_f;
  float* __restrict__ hout = bwd ? hb_out : hf_out;

  __shared__ float x_s[8][80];         // DIN padded; cols 74..79 stay 0
  __shared__ float h_s[8][H_ENC];
  __shared__ int   len_s[8];
  __shared__ int   maxlen_s;

  for (int i = tid; i < 8 * 80; i += 256) (&x_s[0][0])[i] = 0.0f;
  for (int i = tid; i < 8 * H_ENC; i += 256) (&h_s[0][0])[i] = 0.0f;
  if (tid < 8) len_s[tid] = seq_len[b0 + tid];
  __syncthreads();

  if (tid == 0) {
    int m = 0;
    for (int r = 0; r < 8; ++r) m = max(m, len_s[r]);
    maxlen_s = m;
  }

  // acquisition embeddings (constant over t): x[30..57]
  if (tid < 8 * 28) {
    int r = tid / 28, j = tid - r * 28;
    const int* aq = &acq[(b0 + r) * 3];
    float v;
    if (j < 16)      v = Ea0[aq[0] * 16 + j];
    else if (j < 24) v = Ea1[aq[1] * 8 + (j - 16)];
    else             v = Ea2[aq[2] * 4 + (j - 24)];
    x_s[r][30 + j] = v;
  }

  const int u = tid;
  const float bi0 = be[u], bi1 = be[256 + u], bi2 = be[512 + u], bi3 = be[768 + u];
  float c_r[8];
  #pragma unroll
  for (int r = 0; r < 8; ++r) c_r[r] = 0.0f;

  __syncthreads();
  const int maxlen = maxlen_s;

  for (int t = 0; t < maxlen; ++t) {
    // ---- stage x (seq features + date embeddings) ----
    if (tid < 8 * F_SZ) {
      int r = tid / F_SZ, k = tid - r * F_SZ;
      int len = len_s[r];
      int te = bwd ? max(len - 1 - t, 0) : t;
      x_s[r][k] = seq[((b0 + r) * T_SZ + te) * F_SZ + k];
    }
    if (tid < 8 * 16) {
      int r = tid >> 4, j = tid & 15;
      int len = len_s[r];
      int te = bwd ? max(len - 1 - t, 0) : t;
      const int* ym = &ymd[((b0 + r) * T_SZ + te) * 3];
      float v;
      if (j < 8)       v = Es0[ym[0] * 8 + j];
      else if (j < 12) v = Es1[ym[1] * 4 + (j - 8)];
      else             v = Es2[ym[2] * 4 + (j - 12)];
      x_s[r][58 + j] = v;
    }
    __syncthreads();

    // ---- gates: thread u computes all 4 gates of unit u for 8 rows ----
    float a0[8], a1[8], a2[8], a3[8];
    #pragma unroll
    for (int r = 0; r < 8; ++r) { a0[r] = bi0; a1[r] = bi1; a2[r] = bi2; a3[r] = bi3; }

    for (int k = 0; k < DIN_P; k += 4) {
      const float4 w0 = Pih[(k + 0) * 256 + u];
      const float4 w1 = Pih[(k + 1) * 256 + u];
      const float4 w2 = Pih[(k + 2) * 256 + u];
      const float4 w3 = Pih[(k + 3) * 256 + u];
      #pragma unroll
      for (int r = 0; r < 8; ++r) {
        const float4 xv = *reinterpret_cast<const float4*>(&x_s[r][k]);
        a0[r] += w0.x*xv.x + w1.x*xv.y + w2.x*xv.z + w3.x*xv.w;
        a1[r] += w0.y*xv.x + w1.y*xv.y + w2.y*xv.z + w3.y*xv.w;
        a2[r] += w0.z*xv.x + w1.z*xv.y + w2.z*xv.z + w3.z*xv.w;
        a3[r] += w0.w*xv.x + w1.w*xv.y + w2.w*xv.z + w3.w*xv.w;
      }
    }
    for (int k = 0; k < H_ENC; k += 4) {
      const float4 w0 = Phh[(k + 0) * 256 + u];
      const float4 w1 = Phh[(k + 1) * 256 + u];
      const float4 w2 = Phh[(k + 2) * 256 + u];
      const float4 w3 = Phh[(k + 3) * 256 + u];
      #pragma unroll
      for (int r = 0; r < 8; ++r) {
        const float4 hv = *reinterpret_cast<const float4*>(&h_s[r][k]);
        a0[r] += w0.x*hv.x + w1.x*hv.y + w2.x*hv.z + w3.x*hv.w;
        a1[r] += w0.y*hv.x + w1.y*hv.y + w2.y*hv.z + w3.y*hv.w;
        a2[r] += w0.z*hv.x + w1.z*hv.y + w2.z*hv.z + w3.z*hv.w;
        a3[r] += w0.w*hv.x + w1.w*hv.y + w2.w*hv.z + w3.w*hv.w;
      }
    }

    // ---- cell update (masked) ----
    #pragma unroll
    for (int r = 0; r < 8; ++r) {
      if (t < len_s[r]) {
        float ig = sigf(a0[r]);
        float fg = sigf(a1[r]);
        float gg = tanhf(a2[r]);
        float og = sigf(a3[r]);
        float cn = fg * c_r[r] + ig * gg;
        c_r[r] = cn;
        a0[r] = og * tanhf(cn);
      }
    }
    __syncthreads();                     // all h_s reads of this step done
    #pragma unroll
    for (int r = 0; r < 8; ++r) if (t < len_s[r]) h_s[r][u] = a0[r];
    __syncthreads();                     // new h visible; x_s safe to overwrite
  }

  #pragma unroll
  for (int r = 0; r < 8; ++r) hout[(b0 + r) * H_ENC + u] = h_s[r][u];
}

// ---------------- latent: lat = (hf+hb)@WlatT + b; z; dlq0; zero decoder state ----------------
__global__ __launch_bounds__(256) void latent_kernel(
    const float* __restrict__ hf, const float* __restrict__ hb,
    const float2* __restrict__ Plat, const float* __restrict__ b_lat,
    const float* __restrict__ z_noise, const float* __restrict__ seq,
    const int* __restrict__ seq_len,
    float* __restrict__ z, float* __restrict__ dlq,
    float* __restrict__ h1w, float* __restrict__ c1w,
    float* __restrict__ h2w, float* __restrict__ c2w)
{
  const int tid = threadIdx.x;
  const int b0 = blockIdx.x * 16;
  __shared__ float hs[16][H_ENC];
  for (int i = tid; i < 16 * H_ENC; i += 256)
    (&hs[0][0])[i] = hf[b0 * H_ENC + i] + hb[b0 * H_ENC + i];
  __syncthreads();

  const int u = tid;
  const float bm = b_lat[u], bv = b_lat[LATD + u];
  float am[16], av[16];
  #pragma unroll
  for (int r = 0; r < 16; ++r) { am[r] = bm; av[r] = bv; }

  for (int k = 0; k < H_ENC; k += 4) {
    const float2 p0 = Plat[(k + 0) * 256 + u];
    const float2 p1 = Plat[(k + 1) * 256 + u];
    const float2 p2 = Plat[(k + 2) * 256 + u];
    const float2 p3 = Plat[(k + 3) * 256 + u];
    #pragma unroll
    for (int r = 0; r < 16; ++r) {
      const float4 hv = *reinterpret_cast<const float4*>(&hs[r][k]);
      am[r] += p0.x*hv.x + p1.x*hv.y + p2.x*hv.z + p3.x*hv.w;
      av[r] += p0.y*hv.x + p1.y*hv.y + p2.y*hv.z + p3.y*hv.w;
    }
  }
  #pragma unroll
  for (int r = 0; r < 16; ++r) {
    int b = b0 + r;
    z[b * LATD + u] = am[r] + sqrtf(expf(av[r])) * z_noise[b * LATD + u];
  }
  if (u < HD_DEC) {
    #pragma unroll
    for (int r = 0; r < 16; ++r) {
      int b = b0 + r;
      h1w[b * HD_DEC + u] = 0.0f; c1w[b * HD_DEC + u] = 0.0f;
      h2w[b * HD_DEC + u] = 0.0f; c2w[b * HD_DEC + u] = 0.0f;
    }
  }
  if (u < 9) {
    #pragma unroll
    for (int r = 0; r < 16; ++r) {
      int b = b0 + r;
      int len = seq_len[b];
      dlq[b * 9 + u] = seq[(b * T_SZ + (len - 1)) * F_SZ + 21 + u];
    }
  }
}

// ---------------- decoder cell step: LSTM1 + LSTM2 + x=relu(h2@Wg1T+bg1) ----------------
__global__ __launch_bounds__(256) void dec_cell_kernel(
    const float* __restrict__ z, const float* __restrict__ dlq,
    const float* __restrict__ macro,
    float* __restrict__ h1w, float* __restrict__ c1w,
    float* __restrict__ h2w, float* __restrict__ c2w,
    const float4* __restrict__ P1I, const float4* __restrict__ P1H, const float* __restrict__ be1,
    const float4* __restrict__ P2I, const float4* __restrict__ P2H, const float* __restrict__ be2,
    const float* __restrict__ Wg1T, const float* __restrict__ bg1,
    float* __restrict__ xbuf, int t)
{
  const int tid = threadIdx.x;
  const int b0 = blockIdx.x * 16;
  __shared__ float di[16][DEC_IN_P];
  __shared__ float h1s[16][HD_DEC];
  __shared__ float h2s[16][HD_DEC];

  for (int i = tid; i < 16 * DEC_IN_P; i += 256) {
    int r = i / DEC_IN_P, k = i - r * DEC_IN_P;
    int b = b0 + r;
    float v;
    if (k < LATD)            v = z[b * LATD + k];
    else if (k < LATD + 9)   v = dlq[b * 9 + (k - LATD)];
    else if (k < DEC_IN)     v = macro[(b * 12 + t) * 14 + (k - LATD - 9)];
    else                     v = 0.0f;
    di[r][k] = v;
  }
  for (int i = tid; i < 16 * HD_DEC; i += 256) {
    int r = i / HD_DEC, k = i - r * HD_DEC;
    h1s[r][k] = h1w[(b0 + r) * HD_DEC + k];
    h2s[r][k] = h2w[(b0 + r) * HD_DEC + k];
  }

  const int u = tid & 127;
  const int grp = tid >> 7;       // 0/1 -> rows [0..8) / [8..16)
  const int r0 = grp * 8;
  const bool act = u < HD_DEC;

  float c1r[8], c2r[8];
  if (act) {
    #pragma unroll
    for (int r = 0; r < 8; ++r) {
      c1r[r] = c1w[(b0 + r0 + r) * HD_DEC + u];
      c2r[r] = c2w[(b0 + r0 + r) * HD_DEC + u];
    }
  }
  __syncthreads();

  // ---- LSTM1 gates ----
  float a0[8], a1[8], a2[8], a3[8];
  if (act) {
    const float b0g = be1[u], b1g = be1[100 + u], b2g = be1[200 + u], b3g = be1[300 + u];
    #pragma unroll
    for (int r = 0; r < 8; ++r) { a0[r] = b0g; a1[r] = b1g; a2[r] = b2g; a3[r] = b3g; }
    for (int k = 0; k < DEC_IN_P; k += 4) {
      const float4 w0 = P1I[(k + 0) * 100 + u];
      const float4 w1 = P1I[(k + 1) * 100 + u];
      const float4 w2 = P1I[(k + 2) * 100 + u];
      const float4 w3 = P1I[(k + 3) * 100 + u];
      #pragma unroll
      for (int r = 0; r < 8; ++r) {
        const float4 xv = *reinterpret_cast<const float4*>(&di[r0 + r][k]);
        a0[r] += w0.x*xv.x + w1.x*xv.y + w2.x*xv.z + w3.x*xv.w;
        a1[r] += w0.y*xv.x + w1.y*xv.y + w2.y*xv.z + w3.y*xv.w;
        a2[r] += w0.z*xv.x + w1.z*xv.y + w2.z*xv.z + w3.z*xv.w;
        a3[r] += w0.w*xv.x + w1.w*xv.y + w2.w*xv.z + w3.w*xv.w;
      }
    }
    for (int k = 0; k < HD_DEC; k += 4) {
      const float4 w0 = P1H[(k + 0) * 100 + u];
      const float4 w1 = P1H[(k + 1) * 100 + u];
      const float4 w2 = P1H[(k + 2) * 100 + u];
      const float4 w3 = P1H[(k + 3) * 100 + u];
      #pragma unroll
      for (int r = 0; r < 8; ++r) {
        const float4 hv = *reinterpret_cast<const float4*>(&h1s[r0 + r][k]);
        a0[r] += w0.x*hv.x + w1.x*hv.y + w2.x*hv.z + w3.x*hv.w;
        a1[r] += w0.y*hv.x + w1.y*hv.y + w2.y*hv.z + w3.y*hv.w;
        a2[r] += w0.z*hv.x + w1.z*hv.y + w2.z*hv.z + w3.z*hv.w;
        a3[r] += w0.w*hv.x + w1.w*hv.y + w2.w*hv.z + w3.w*hv.w;
      }
    }
  }
  __syncthreads();                 // h1s reads complete
  if (act) {
    #pragma unroll
    for (int r = 0; r < 8; ++r) {
      float ig = sigf(a0[r]), fg = sigf(a1[r]), gg = tanhf(a2[r]), og = sigf(a3[r]);
      float cn = fg * c1r[r] + ig * gg;
      float hn = og * tanhf(cn);
      int b = b0 + r0 + r;
      h1s[r0 + r][u] = hn;
      h1w[b * HD_DEC + u] = hn;
      c1w[b * HD_DEC + u] = cn;
    }
  }
  __syncthreads();                 // new h1 visible

  // ---- LSTM2 gates (x = new h1, h = old h2) ----
  if (act) {
    const float b0g = be2[u], b1g = be2[100 + u], b2g = be2[200 + u], b3g = be2[300 + u];
    #pragma unroll
    for (int r = 0; r < 8; ++r) { a0[r] = b0g; a1[r] = b1g; a2[r] = b2g; a3[r] = b3g; }
    for (int k = 0; k < HD_DEC; k += 4) {
      const float4 w0 = P2I[(k + 0) * 100 + u];
      const float4 w1 = P2I[(k + 1) * 100 + u];
      const float4 w2 = P2I[(k + 2) * 100 + u];
      const float4 w3 = P2I[(k + 3) * 100 + u];
      #pragma unroll
      for (int r = 0; r < 8; ++r) {
        const float4 hv = *reinterpret_cast<const float4*>(&h1s[r0 + r][k]);
        a0[r] += w0.x*hv.x + w1.x*hv.y + w2.x*hv.z + w3.x*hv.w;
        a1[r] += w0.y*hv.x + w1.y*hv.y + w2.y*hv.z + w3.y*hv.w;
        a2[r] += w0.z*hv.x + w1.z*hv.y + w2.z*hv.z + w3.z*hv.w;
        a3[r] += w0.w*hv.x + w1.w*hv.y + w2.w*hv.z + w3.w*hv.w;
      }
    }
    for (int k = 0; k < HD_DEC; k += 4) {
      const float4 w0 = P2H[(k + 0) * 100 + u];
      const float4 w1 = P2H[(k + 1) * 100 + u];
      const float4 w2 = P2H[(k + 2) * 100 + u];
      const float4 w3 = P2H[(k + 3) * 100 + u];
      #pragma unroll
      for (int r = 0; r < 8; ++r) {
        const float4 hv = *reinterpret_cast<const float4*>(&h2s[r0 + r][k]);
        a0[r] += w0.x*hv.x + w1.x*hv.y + w2.x*hv.z + w3.x*hv.w;
        a1[r] += w0.y*hv.x + w1.y*hv.y + w2.y*hv.z + w3.y*hv.w;
        a2[r] += w0.z*hv.x + w1.z*hv.y + w2.z*hv.z + w3.z*hv.w;
        a3[r] += w0.w*hv.x + w1.w*hv.y + w2.w*hv.z + w3.w*hv.w;
      }
    }
  }
  __syncthreads();                 // h2s reads complete
  if (act) {
    #pragma unroll
    for (int r = 0; r < 8; ++r) {
      float ig = sigf(a0[r]), fg = sigf(a1[r]), gg = tanhf(a2[r]), og = sigf(a3[r]);
      float cn = fg * c2r[r] + ig * gg;
      float hn = og * tanhf(cn);
      int b = b0 + r0 + r;
      h2s[r0 + r][u] = hn;
      h2w[b * HD_DEC + u] = hn;
      c2w[b * HD_DEC + u] = cn;
    }
  }
  __syncthreads();                 // new h2 visible

  // ---- x = relu(h2 @ Wg1T + bg1) ----
  for (int p = tid; p < 16 * 25; p += 256) {
    int r = p / 25, c = p - r * 25;
    float s = bg1[c];
    for (int k = 0; k < HD_DEC; k += 4) {
      const float4 hv = *reinterpret_cast<const float4*>(&h2s[r][k]);
      s += hv.x * Wg1T[k * 25 + c] + hv.y * Wg1T[(k + 1) * 25 + c]
         + hv.z * Wg1T[(k + 2) * 25 + c] + hv.w * Wg1T[(k + 3) * 25 + c];
    }
    xbuf[(b0 + r) * 25 + c] = fmaxf(s, 0.0f);
  }
}

// ---------------- decoder batchnorm stats (deterministic tree reduce) ----------------
__global__ __launch_bounds__(256) void dec_stats_kernel(
    const float* __restrict__ xbuf, float* __restrict__ muv, float* __restrict__ rstdv)
{
  const int col = blockIdx.x;
  const int tid = threadIdx.x;
  __shared__ float red[256];
  float v[16];
  float s = 0.0f;
  #pragma unroll
  for (int i = 0; i < 16; ++i) { v[i] = xbuf[(tid + 256 * i) * 25 + col]; s += v[i]; }
  red[tid] = s; __syncthreads();
  for (int off = 128; off >= 1; off >>= 1) {
    if (tid < off) red[tid] += red[tid + off];
    __syncthreads();
  }
  float mean = red[0] / (float)B_SZ;
  __syncthreads();
  float s2 = 0.0f;
  #pragma unroll
  for (int i = 0; i < 16; ++i) { float d = v[i] - mean; s2 += d * d; }
  red[tid] = s2; __syncthreads();
  for (int off = 128; off >= 1; off >>= 1) {
    if (tid < off) red[tid] += red[tid + off];
    __syncthreads();
  }
  if (tid == 0) {
    muv[col] = mean;
    rstdv[col] = rsqrtf(red[0] / (float)B_SZ + 1e-5f);
  }
}

// ---------------- decoder normalize + dlq = xn@Wg2T + bg2, write output ----------------
__global__ __launch_bounds__(256) void dec_out_kernel(
    const float* __restrict__ xbuf, const float* __restrict__ muv, const float* __restrict__ rstdv,
    const float* __restrict__ gamma, const float* __restrict__ beta,
    const float* __restrict__ Wg2, const float* __restrict__ bg2,
    float* __restrict__ dlq, float* __restrict__ out, int t)
{
  int b = blockIdx.x * 256 + threadIdx.x;
  float xn[25];
  #pragma unroll
  for (int c = 0; c < 25; ++c)
    xn[c] = gamma[c] * (xbuf[b * 25 + c] - muv[c]) * rstdv[c] + beta[c];
  #pragma unroll
  for (int j = 0; j < 9; ++j) {
    float s = bg2[j];
    #pragma unroll
    for (int c = 0; c < 25; ++c) s += xn[c] * Wg2[j * 25 + c];
    dlq[b * 9 + j] = s;
    out[b * 108 + j * 12 + t] = s;
  }
}

// ---------------- host launch ----------------
extern "C" void kernel_launch(void* const* d_in, const int* in_sizes, int n_in,
                              void* d_out, int out_size, void* d_ws, size_t ws_size,
                              hipStream_t stream)
{
  const float* seq     = (const float*)d_in[0];
  const int*   seq_len = (const int*)  d_in[1];
  const int*   ymd     = (const int*)  d_in[2];
  const int*   acq     = (const int*)  d_in[3];
  const float* macro   = (const float*)d_in[4];
  const float* z_noise = (const float*)d_in[5];
  const float* Ea0 = (const float*)d_in[6];
  const float* Ea1 = (const float*)d_in[7];
  const float* Ea2 = (const float*)d_in[8];
  const float* Es0 = (const float*)d_in[9];
  const float* Es1 = (const float*)d_in[10];
  const float* Es2 = (const float*)d_in[11];
  const float* Wih_f = (const float*)d_in[12];
  const float* Whh_f = (const float*)d_in[13];
  const float* bih_f = (const float*)d_in[14];
  const float* bhh_f = (const float*)d_in[15];
  const float* Wih_b = (const float*)d_in[16];
  const float* Whh_b = (const float*)d_in[17];
  const float* bih_b = (const float*)d_in[18];
  const float* bhh_b = (const float*)d_in[19];
  const float* W_lat = (const float*)d_in[20];
  const float* b_lat = (const float*)d_in[21];
  const float* Wih1  = (const float*)d_in[22];
  const float* Whh1  = (const float*)d_in[23];
  const float* bih1  = (const float*)d_in[24];
  const float* bhh1  = (const float*)d_in[25];
  const float* Wih2  = (const float*)d_in[26];
  const float* Whh2  = (const float*)d_in[27];
  const float* bih2  = (const float*)d_in[28];
  const float* bhh2  = (const float*)d_in[29];
  const float* Wg1   = (const float*)d_in[30];
  const float* bg1   = (const float*)d_in[31];
  const float* gamma = (const float*)d_in[32];
  const float* beta  = (const float*)d_in[33];
  const float* Wg2   = (const float*)d_in[34];
  const float* bg2   = (const float*)d_in[35];

  float* ws  = (float*)d_ws;
  float* out = (float*)d_out;

  float* pihF = ws + OFF_PIH_F;
  float* phhF = ws + OFF_PHH_F;
  float* pihB = ws + OFF_PIH_B;
  float* phhB = ws + OFF_PHH_B;
  float* plat = ws + OFF_PLAT;
  float* p1i  = ws + OFF_P1I;
  float* p1h  = ws + OFF_P1H;
  float* p2i  = ws + OFF_P2I;
  float* p2h  = ws + OFF_P2H;
  float* wg1T = ws + OFF_WG1T;
  float* be_f = ws + OFF_BE_F;
  float* be_b = ws + OFF_BE_B;
  float* be1  = ws + OFF_BE1;
  float* be2  = ws + OFF_BE2;
  float* hf   = ws + OFF_HF;
  float* hb   = ws + OFF_HB;
  float* z    = ws + OFF_Z;
  float* h1w  = ws + OFF_H1;
  float* c1w  = ws + OFF_C1;
  float* h2w  = ws + OFF_H2;
  float* c2w  = ws + OFF_C2;
  float* dlq  = ws + OFF_DLQ;
  float* xbuf = ws + OFF_XBUF;
  float* muv  = ws + OFF_MU;
  float* rstdv= ws + OFF_RSTD;

  PrepArgs pa;
  int ji = 0;
  auto PK = [&](const float* s, float* d, int U, int C, int Kp, int G) {
    pa.j[ji].src = s; pa.j[ji].src2 = nullptr; pa.j[ji].dst = d;
    pa.j[ji].U = U; pa.j[ji].C = C; pa.j[ji].Kp = Kp; pa.j[ji].G = G; ++ji;
  };
  auto BS = [&](const float* a, const float* b, float* d, int n) {
    pa.j[ji].src = a; pa.j[ji].src2 = b; pa.j[ji].dst = d;
    pa.j[ji].U = n; pa.j[ji].C = 0; pa.j[ji].Kp = 0; pa.j[ji].G = 0; ++ji;
  };
  PK(Wih_f, pihF, 256, 74, 76, 4);
  PK(Whh_f, phhF, 256, 256, 256, 4);
  PK(Wih_b, pihB, 256, 74, 76, 4);
  PK(Whh_b, phhB, 256, 256, 256, 4);
  PK(W_lat, plat, 256, 256, 256, 2);
  PK(Wih1,  p1i,  100, 279, 280, 4);
  PK(Whh1,  p1h,  100, 100, 100, 4);
  PK(Wih2,  p2i,  100, 100, 100, 4);
  PK(Whh2,  p2h,  100, 100, 100, 4);
  PK(Wg1,   wg1T, 25, 100, 100, 1);
  BS(bih_f, bhh_f, be_f, 1024);
  BS(bih_b, bhh_b, be_b, 1024);
  BS(bih1,  bhh1,  be1,  400);
  BS(bih2,  bhh2,  be2,  400);

  prep_kernel<<<512, 256, 0, stream>>>(pa);

  enc_kernel<<<1024, 256, 0, stream>>>(
      seq, seq_len, ymd, acq, Ea0, Ea1, Ea2, Es0, Es1, Es2,
      (const float4*)pihF, (const float4*)phhF, be_f,
      (const float4*)pihB, (const float4*)phhB, be_b, hf, hb);

  latent_kernel<<<256, 256, 0, stream>>>(
      hf, hb, (const float2*)plat, b_lat, z_noise, seq, seq_len,
      z, dlq, h1w, c1w, h2w, c2w);

  for (int t = 0; t < 12; ++t) {
    dec_cell_kernel<<<256, 256, 0, stream>>>(
        z, dlq, macro, h1w, c1w, h2w, c2w,
        (const float4*)p1i, (const float4*)p1h, be1,
        (const float4*)p2i, (const float4*)p2h, be2, wg1T, bg1, xbuf, t);
    dec_stats_kernel<<<25, 256, 0, stream>>>(xbuf, muv, rstdv);
    dec_out_kernel<<<16, 256, 0, stream>>>(
        xbuf, muv, rstdv, gamma, beta, Wg2, bg2, dlq, out, t);
  }
}